// Round 3
// baseline (1615.542 us; speedup 1.0000x reference)
//
#include <hip/hip_runtime.h>
#include <math.h>
#include <float.h>

namespace {
constexpr int kH = 8192;        // hidden (K)
constexpr int kE = 256;         // experts (N)
constexpr int kTopK = 8;
constexpr int kTok = 8192;      // B*S rows (M)
constexpr int kIdxOff = kTok * kTopK;          // 65536
constexpr int kLogitsOff = 2 * kTok * kTopK;   // 131072
// GEMM tiling
constexpr int kBT = 32;                  // tokens per block
constexpr int kKC = 4;                   // split-K chunks
constexpr int kKchunk = kH / kKC;        // 2048
constexpr int kKT = 32;                  // k per LDS tile
constexpr int kPadT = 37;                // padded token stride (<=2-way write aliasing)
constexpr int kCand = 16;                // candidates kept for refinement
constexpr float kEps = 1e-3f;            // fp32-ordering trust margin (~500x fp32 error)
// ws layout: Wt fp32 [256][8192] @0 (8MB); partials 1..3 @8MB (24MB) = 32MB total
constexpr size_t kWtFloats = (size_t)kE * kH;
constexpr size_t kPartFloats = (size_t)kTok * kE;
}

// ---------------- Kernel A: W[k][e] -> Wt[e][k] ----------------------------
__global__ __launch_bounds__(1024)
void transpose_w(const float* __restrict__ W, float* __restrict__ Wt) {
    __shared__ float tile[32][33];
    const int k0 = blockIdx.x * 32, e0 = blockIdx.y * 32;
    const int tx = threadIdx.x, ty = threadIdx.y;
    tile[ty][tx] = W[(size_t)(k0 + ty) * kE + (e0 + tx)];
    __syncthreads();
    Wt[(size_t)(e0 + ty) * kH + (k0 + tx)] = tile[tx][ty];
}

// ---------------- Kernel B: split-K fp32 GEMM ------------------------------
// block = 32 tokens x 256 experts x 2048 k. 256 thr / 4 waves: lane owns 4
// experts, wave owns 8 tokens -> acc[8][4]. Double-buffered x-tile in LDS,
// one barrier per 32-k tile. Grid 256x4 = 1024 blocks -> 4 blocks/CU.
__global__ __launch_bounds__(256, 4)
void router_gemm(const float* __restrict__ x, const float* __restrict__ Wr,
                 float* __restrict__ p0, float* __restrict__ pws)
{
    __shared__ float xs[2][kKT][kPadT];
    const int tid  = threadIdx.x;
    const int lane = tid & 63;
    const int w    = tid >> 6;
    const int t0   = blockIdx.x * kBT;
    const int kc   = blockIdx.y;
    const int kbase = kc * kKchunk;

    float acc[8][4];
    #pragma unroll
    for (int t = 0; t < 8; ++t)
        #pragma unroll
        for (int m = 0; m < 4; ++m) acc[t][m] = 0.f;

    // staging map: each thread loads ONE float4 per tile
    const int tt = tid >> 3;            // token 0..31
    const int s  = tid & 7;             // k-slot (4 floats each)
    const float* xsrc = x + (size_t)(t0 + tt) * kH + kbase + (s << 2);

    // prologue: tile 0
    {
        const float4 a = *reinterpret_cast<const float4*>(xsrc);
        xs[0][(s << 2) + 0][tt] = a.x;
        xs[0][(s << 2) + 1][tt] = a.y;
        xs[0][(s << 2) + 2][tt] = a.z;
        xs[0][(s << 2) + 3][tt] = a.w;
    }
    __syncthreads();

    constexpr int kNT = kKchunk / kKT;   // 64 tiles
    int cur = 0;
    for (int tile = 0; tile < kNT; ++tile) {
        // issue next tile's global load early (latency hidden under compute)
        float4 nx;
        const bool more = (tile + 1) < kNT;
        if (more)
            nx = *reinterpret_cast<const float4*>(xsrc + (size_t)(tile + 1) * kKT);

        const float* wp = Wr + (size_t)(kbase + tile * kKT) * kE + (lane << 2);
        #pragma unroll 8
        for (int j = 0; j < kKT; ++j) {
            const float4 wv = *reinterpret_cast<const float4*>(wp);
            wp += kE;
            const float* xj = &xs[cur][j][w << 3];
            const float4 xa = *reinterpret_cast<const float4*>(xj);
            const float4 xb = *reinterpret_cast<const float4*>(xj + 4);
            const float xv[8] = {xa.x, xa.y, xa.z, xa.w, xb.x, xb.y, xb.z, xb.w};
            #pragma unroll
            for (int t = 0; t < 8; ++t) {
                acc[t][0] = fmaf(xv[t], wv.x, acc[t][0]);
                acc[t][1] = fmaf(xv[t], wv.y, acc[t][1]);
                acc[t][2] = fmaf(xv[t], wv.z, acc[t][2]);
                acc[t][3] = fmaf(xv[t], wv.w, acc[t][3]);
            }
        }

        if (more) {
            const int nxt = cur ^ 1;
            xs[nxt][(s << 2) + 0][tt] = nx.x;
            xs[nxt][(s << 2) + 1][tt] = nx.y;
            xs[nxt][(s << 2) + 2][tt] = nx.z;
            xs[nxt][(s << 2) + 3][tt] = nx.w;
            __syncthreads();             // writes to nxt visible before next tile
            cur = nxt;
        }
    }

    float* dst = (kc == 0) ? p0 : (pws + (size_t)(kc - 1) * kPartFloats);
    #pragma unroll
    for (int t = 0; t < 8; ++t) {
        const int token = t0 + (w << 3) + t;
        float4 o;
        o.x = acc[t][0]; o.y = acc[t][1]; o.z = acc[t][2]; o.w = acc[t][3];
        *reinterpret_cast<float4*>(dst + (size_t)token * kE + (lane << 2)) = o;
    }
}

// ---------------- Kernel C: combine + select + (rare) fp64 refine ----------
// 256 threads = 4 waves, one row per wave.
__global__ __launch_bounds__(256)
void combine_select(const float* __restrict__ x, const float* __restrict__ Wt,
                    const float* __restrict__ pws, float* __restrict__ out)
{
    const int lane = threadIdx.x & 63;
    const int w    = threadIdx.x >> 6;
    const int row  = blockIdx.x * 4 + w;
    float* logits = out + kLogitsOff;
    const size_t rb = (size_t)row * kE + (lane << 2);

    float4 s = *reinterpret_cast<const float4*>(logits + rb);   // partial 0
    #pragma unroll
    for (int p = 0; p < kKC - 1; ++p) {
        const float4 q = *reinterpret_cast<const float4*>(pws + (size_t)p * kPartFloats + rb);
        s.x += q.x; s.y += q.y; s.z += q.z; s.w += q.w;
    }
    *reinterpret_cast<float4*>(logits + rb) = s;                // final logits

    float v0 = s.x, v1 = s.y, v2 = s.z, v3 = s.w;
    float myv = -FLT_MAX; int myi = -1;
    #pragma unroll
    for (int r = 0; r < kCand; ++r) {
        float bv = v0; int bi = (lane << 2);
        if (v1 > bv) { bv = v1; bi = (lane << 2) + 1; }
        if (v2 > bv) { bv = v2; bi = (lane << 2) + 2; }
        if (v3 > bv) { bv = v3; bi = (lane << 2) + 3; }
        #pragma unroll
        for (int off = 32; off > 0; off >>= 1) {
            const float ov = __shfl_xor(bv, off, 64);
            const int   oi = __shfl_xor(bi, off, 64);
            if (ov > bv || (ov == bv && oi < bi)) { bv = ov; bi = oi; }
        }
        if (lane == r) { myv = bv; myi = bi; }
        if ((bi >> 2) == lane) {
            const int m = bi & 3;
            if      (m == 0) v0 = -FLT_MAX;
            else if (m == 1) v1 = -FLT_MAX;
            else if (m == 2) v2 = -FLT_MAX;
            else             v3 = -FLT_MAX;
        }
    }

    const float nv = __shfl_down(myv, 1, 64);
    const unsigned long long amb = __ballot(lane < 8 && (myv - nv) < kEps);

    if (amb == 0ull) {
        const float m = __shfl(myv, 0, 64);
        const float e = (lane < kTopK) ? expf(myv - m) : 0.f;
        float t = e;
        #pragma unroll
        for (int off = 1; off < 8; off <<= 1) t += __shfl_xor(t, off, 64);
        if (lane < kTopK) {
            out[(size_t)row * kTopK + lane]           = e / t;
            out[kIdxOff + (size_t)row * kTopK + lane] = (float)myi;
        }
    } else {
        // fp64 recompute of the 16 candidates (coalesced: whole wave per column)
        const float* xr = x + (size_t)row * kH;
        double dv = -1.0e300;
        #pragma unroll 1
        for (int c = 0; c < kCand; ++c) {
            const int idx = __shfl(myi, c, 64);
            const float* wr = Wt + (size_t)idx * kH;
            double a = 0.0;
            for (int k = (lane << 2); k < kH; k += 256) {
                const float4 xv = *reinterpret_cast<const float4*>(xr + k);
                const float4 wv = *reinterpret_cast<const float4*>(wr + k);
                a = fma((double)xv.x, (double)wv.x, a);
                a = fma((double)xv.y, (double)wv.y, a);
                a = fma((double)xv.z, (double)wv.z, a);
                a = fma((double)xv.w, (double)wv.w, a);
            }
            #pragma unroll
            for (int off = 32; off > 0; off >>= 1) a += __shfl_xor(a, off, 64);
            if (lane == c) dv = a;
        }
        double cv = dv; int ci = myi;
        double mx = 0.0, ssum = 0.0, keepv = 0.0; int keepi = 0;
        #pragma unroll 1
        for (int r = 0; r < kTopK; ++r) {
            double bv = cv; int bi = ci;
            #pragma unroll
            for (int off = 32; off > 0; off >>= 1) {
                const double ov = __shfl_xor(bv, off, 64);
                const int    oi = __shfl_xor(bi, off, 64);
                if (ov > bv || (ov == bv && oi < bi)) { bv = ov; bi = oi; }
            }
            if (r == 0) mx = bv;
            ssum += exp(bv - mx);
            if (lane == r) { keepv = bv; keepi = bi; }
            if (ci == bi) cv = -1.0e300;
        }
        if (lane < kTopK) {
            out[(size_t)row * kTopK + lane]           = (float)(exp(keepv - mx) / ssum);
            out[kIdxOff + (size_t)row * kTopK + lane] = (float)keepi;
        }
    }
}

extern "C" void kernel_launch(void* const* d_in, const int* in_sizes, int n_in,
                              void* d_out, int out_size, void* d_ws, size_t ws_size,
                              hipStream_t stream) {
    const float* x  = (const float*)d_in[0];
    const float* Wr = (const float*)d_in[1];
    float* out = (float*)d_out;
    float* Wt  = (float*)d_ws;                      // 8 MB
    float* pws = (float*)d_ws + kWtFloats;          // 24 MB
    (void)in_sizes; (void)n_in; (void)out_size; (void)ws_size;

    hipLaunchKernelGGL(transpose_w, dim3(kH / 32, kE / 32), dim3(32, 32), 0, stream, Wr, Wt);
    hipLaunchKernelGGL(router_gemm, dim3(kTok / kBT, kKC), dim3(256), 0, stream,
                       x, Wr, out + kLogitsOff, pws);
    hipLaunchKernelGGL(combine_select, dim3(kTok / 4), dim3(256), 0, stream, x, Wt, pws, out);
}

// Round 4
// 324.122 us; speedup vs baseline: 4.9844x; 4.9844x over previous
//
#include <hip/hip_runtime.h>
#include <math.h>
#include <float.h>

typedef _Float16 half8 __attribute__((ext_vector_type(8)));
typedef float f32x4 __attribute__((ext_vector_type(4)));

namespace {
constexpr int kH = 8192, kE = 256, kTopK = 8, kTok = 8192;
constexpr int kIdxOff = kTok * kTopK;          // 65536
constexpr int kLogitsOff = 2 * kTok * kTopK;   // 131072
constexpr int kBM = 128, kBN = 128, kBK = 32;
constexpr int kPadH = 40;                      // LDS row stride in halfs (80B: 2-way=free)
constexpr int kCand = 16;
constexpr float kEps = 3e-4f;                  // gap-trust margin (~20x max fp16x3 error)
constexpr float kInvScale = 1.0f / 262144.0f;  // 2^-18 (x*2^10, W*2^8)
// ws layout in floats: Wt fp32 [256][8192] | Wth fp16 | Wtl fp16 | partials
constexpr size_t kWtF   = (size_t)kE * kH;             // 2,097,152 floats (8MB)
constexpr size_t kWtlF  = kWtF + (size_t)kE * kH / 2;  // Wth is 4MB
constexpr size_t kPartF = kWtF + (size_t)kE * kH;      // 16MB offset
constexpr size_t kPartStride = (size_t)kTok * kE;      // 8MB per partial
}

// ---------- Kernel A: W[k][e] -> Wt fp32 [e][k], Wth/Wtl fp16 (W*256 split) --
__global__ __launch_bounds__(1024)
void prep_w(const float* __restrict__ W, float* __restrict__ Wt,
            _Float16* __restrict__ Wth, _Float16* __restrict__ Wtl) {
    __shared__ float tile[32][33];
    const int k0 = blockIdx.x * 32, e0 = blockIdx.y * 32;
    const int tx = threadIdx.x, ty = threadIdx.y;
    tile[ty][tx] = W[(size_t)(k0 + ty) * kE + (e0 + tx)];
    __syncthreads();
    const float v = tile[tx][ty];
    const size_t o = (size_t)(e0 + ty) * kH + (k0 + tx);
    Wt[o] = v;
    const float vs = v * 256.0f;
    const _Float16 h = (_Float16)vs;
    Wth[o] = h;
    Wtl[o] = (_Float16)(vs - (float)h);
}

// ---------- Kernel B: fp16x3 MFMA GEMM, 128x128 tile, split-K -----------------
// 256 thr = 4 waves (2x2). Wave tile 64x64 = 4x4 frags of 16x16x32_f16.
// acc += Ah*Bh + Ah*Bl + Al*Bh (all scaled 2^18; one accumulator).
__global__ __launch_bounds__(256, 2)
void router_gemm_mfma(const float* __restrict__ x,
                      const _Float16* __restrict__ Wth,
                      const _Float16* __restrict__ Wtl,
                      float* __restrict__ p0, float* __restrict__ pws,
                      int kchunk)
{
    __shared__ _Float16 sxh[kBM][kPadH], sxl[kBM][kPadH];
    __shared__ _Float16 swh[kBN][kPadH], swl[kBN][kPadH];

    const int tid  = threadIdx.x;
    const int lane = tid & 63;
    const int w    = tid >> 6;
    const int wm   = w >> 1, wn = w & 1;
    const int t0   = blockIdx.x * kBM;
    const int e0   = blockIdx.y * kBN;
    const int kc   = blockIdx.z;
    const int kbase = kc * kchunk;
    const int nsteps = kchunk / kBK;

    f32x4 acc[4][4];
    #pragma unroll
    for (int m = 0; m < 4; ++m)
        #pragma unroll
        for (int n = 0; n < 4; ++n) {
            acc[m][n][0] = 0.f; acc[m][n][1] = 0.f;
            acc[m][n][2] = 0.f; acc[m][n][3] = 0.f;
        }

    // staging map: row = tid>>1 (0..127), 16-elem col group = (tid&1)*16
    const int srow = tid >> 1;
    const int scg  = (tid & 1) << 4;
    const float*    xp  = x   + (size_t)(t0 + srow) * kH + kbase + scg;
    const _Float16* whp = Wth + (size_t)(e0 + srow) * kH + kbase + scg;
    const _Float16* wlp = Wtl + (size_t)(e0 + srow) * kH + kbase + scg;

    float4 xv0, xv1, xv2, xv3;
    uint4  wh0, wh1, wl0, wl1;
    {   // prologue loads (step 0)
        xv0 = *reinterpret_cast<const float4*>(xp);
        xv1 = *reinterpret_cast<const float4*>(xp + 4);
        xv2 = *reinterpret_cast<const float4*>(xp + 8);
        xv3 = *reinterpret_cast<const float4*>(xp + 12);
        wh0 = *reinterpret_cast<const uint4*>(whp);
        wh1 = *reinterpret_cast<const uint4*>(whp + 8);
        wl0 = *reinterpret_cast<const uint4*>(wlp);
        wl1 = *reinterpret_cast<const uint4*>(wlp + 8);
    }

    const int fr = lane & 15;          // frag row within 16
    const int fk = (lane >> 4) << 3;   // frag k offset (halfs), 16B-aligned

    for (int t = 0; t < nsteps; ++t) {
        // convert + LDS write of step t
        float xf[16];
        xf[0]=xv0.x; xf[1]=xv0.y; xf[2]=xv0.z; xf[3]=xv0.w;
        xf[4]=xv1.x; xf[5]=xv1.y; xf[6]=xv1.z; xf[7]=xv1.w;
        xf[8]=xv2.x; xf[9]=xv2.y; xf[10]=xv2.z; xf[11]=xv2.w;
        xf[12]=xv3.x; xf[13]=xv3.y; xf[14]=xv3.z; xf[15]=xv3.w;
        half8 h0, h1, l0, l1;
        #pragma unroll
        for (int i = 0; i < 8; ++i) {
            const float sA = xf[i] * 1024.0f;
            const _Float16 hA = (_Float16)sA;
            h0[i] = hA; l0[i] = (_Float16)(sA - (float)hA);
            const float sB = xf[i + 8] * 1024.0f;
            const _Float16 hB = (_Float16)sB;
            h1[i] = hB; l1[i] = (_Float16)(sB - (float)hB);
        }
        *reinterpret_cast<half8*>(&sxh[srow][scg])     = h0;
        *reinterpret_cast<half8*>(&sxh[srow][scg + 8]) = h1;
        *reinterpret_cast<half8*>(&sxl[srow][scg])     = l0;
        *reinterpret_cast<half8*>(&sxl[srow][scg + 8]) = l1;
        *reinterpret_cast<uint4*>(&swh[srow][scg])     = wh0;
        *reinterpret_cast<uint4*>(&swh[srow][scg + 8]) = wh1;
        *reinterpret_cast<uint4*>(&swl[srow][scg])     = wl0;
        *reinterpret_cast<uint4*>(&swl[srow][scg + 8]) = wl1;
        __syncthreads();

        // issue step t+1 global loads early (hide under MFMA)
        if (t + 1 < nsteps) {
            const size_t o = (size_t)(t + 1) * kBK;
            xv0 = *reinterpret_cast<const float4*>(xp + o);
            xv1 = *reinterpret_cast<const float4*>(xp + o + 4);
            xv2 = *reinterpret_cast<const float4*>(xp + o + 8);
            xv3 = *reinterpret_cast<const float4*>(xp + o + 12);
            wh0 = *reinterpret_cast<const uint4*>(whp + o);
            wh1 = *reinterpret_cast<const uint4*>(whp + o + 8);
            wl0 = *reinterpret_cast<const uint4*>(wlp + o);
            wl1 = *reinterpret_cast<const uint4*>(wlp + o + 8);
        }

        // fragment reads + 48 MFMAs
        half8 ah[4], al[4];
        #pragma unroll
        for (int m = 0; m < 4; ++m) {
            ah[m] = *reinterpret_cast<const half8*>(&sxh[(wm << 6) + (m << 4) + fr][fk]);
            al[m] = *reinterpret_cast<const half8*>(&sxl[(wm << 6) + (m << 4) + fr][fk]);
        }
        #pragma unroll
        for (int n = 0; n < 4; ++n) {
            const half8 bh = *reinterpret_cast<const half8*>(&swh[(wn << 6) + (n << 4) + fr][fk]);
            const half8 bl = *reinterpret_cast<const half8*>(&swl[(wn << 6) + (n << 4) + fr][fk]);
            #pragma unroll
            for (int m = 0; m < 4; ++m) {
                acc[m][n] = __builtin_amdgcn_mfma_f32_16x16x32_f16(ah[m], bh, acc[m][n], 0, 0, 0);
                acc[m][n] = __builtin_amdgcn_mfma_f32_16x16x32_f16(ah[m], bl, acc[m][n], 0, 0, 0);
                acc[m][n] = __builtin_amdgcn_mfma_f32_16x16x32_f16(al[m], bh, acc[m][n], 0, 0, 0);
            }
        }
        __syncthreads();
    }

    // epilogue: D(lane,reg) -> row=(lane>>4)*4+reg, col=lane&15
    float* dst = (kc == 0) ? p0 : (pws + (size_t)(kc - 1) * kPartStride);
    const int r0 = (lane >> 4) << 2;
    const int c0 = lane & 15;
    #pragma unroll
    for (int m = 0; m < 4; ++m)
        #pragma unroll
        for (int n = 0; n < 4; ++n) {
            const int col = e0 + (wn << 6) + (n << 4) + c0;
            #pragma unroll
            for (int r = 0; r < 4; ++r) {
                const int row = t0 + (wm << 6) + (m << 4) + r0 + r;
                dst[(size_t)row * kE + col] = acc[m][n][r] * kInvScale;
            }
        }
}

// ---------- Kernel C: combine + select + (rare) fp64 refine ------------------
__global__ __launch_bounds__(256)
void combine_select(const float* __restrict__ x, const float* __restrict__ Wt,
                    const float* __restrict__ pws, float* __restrict__ out,
                    int npart)
{
    const int lane = threadIdx.x & 63;
    const int w    = threadIdx.x >> 6;
    const int row  = blockIdx.x * 4 + w;
    float* logits = out + kLogitsOff;
    const size_t rb = (size_t)row * kE + (lane << 2);

    float4 s = *reinterpret_cast<const float4*>(logits + rb);   // partial 0
    for (int p = 0; p < npart; ++p) {
        const float4 q = *reinterpret_cast<const float4*>(pws + (size_t)p * kPartStride + rb);
        s.x += q.x; s.y += q.y; s.z += q.z; s.w += q.w;
    }
    *reinterpret_cast<float4*>(logits + rb) = s;                // final logits

    float v0 = s.x, v1 = s.y, v2 = s.z, v3 = s.w;
    float myv = -FLT_MAX; int myi = -1;
    #pragma unroll
    for (int r = 0; r < kCand; ++r) {
        float bv = v0; int bi = (lane << 2);
        if (v1 > bv) { bv = v1; bi = (lane << 2) + 1; }
        if (v2 > bv) { bv = v2; bi = (lane << 2) + 2; }
        if (v3 > bv) { bv = v3; bi = (lane << 2) + 3; }
        #pragma unroll
        for (int off = 32; off > 0; off >>= 1) {
            const float ov = __shfl_xor(bv, off, 64);
            const int   oi = __shfl_xor(bi, off, 64);
            if (ov > bv || (ov == bv && oi < bi)) { bv = ov; bi = oi; }
        }
        if (lane == r) { myv = bv; myi = bi; }
        if ((bi >> 2) == lane) {
            const int m = bi & 3;
            if      (m == 0) v0 = -FLT_MAX;
            else if (m == 1) v1 = -FLT_MAX;
            else if (m == 2) v2 = -FLT_MAX;
            else             v3 = -FLT_MAX;
        }
    }

    const float nv = __shfl_down(myv, 1, 64);
    const unsigned long long amb = __ballot(lane < 8 && (myv - nv) < kEps);

    if (amb == 0ull) {
        const float m = __shfl(myv, 0, 64);
        const float e = (lane < kTopK) ? expf(myv - m) : 0.f;
        float t = e;
        #pragma unroll
        for (int off = 1; off < 8; off <<= 1) t += __shfl_xor(t, off, 64);
        if (lane < kTopK) {
            out[(size_t)row * kTopK + lane]           = e / t;
            out[kIdxOff + (size_t)row * kTopK + lane] = (float)myi;
        }
    } else {
        // fp64 recompute of the 16 candidates (exact tie-break, matches ref)
        const float* xr = x + (size_t)row * kH;
        double dv = -1.0e300;
        #pragma unroll 1
        for (int c = 0; c < kCand; ++c) {
            const int idx = __shfl(myi, c, 64);
            const float* wr = Wt + (size_t)idx * kH;
            double a = 0.0;
            for (int k = (lane << 2); k < kH; k += 256) {
                const float4 xv = *reinterpret_cast<const float4*>(xr + k);
                const float4 wv = *reinterpret_cast<const float4*>(wr + k);
                a = fma((double)xv.x, (double)wv.x, a);
                a = fma((double)xv.y, (double)wv.y, a);
                a = fma((double)xv.z, (double)wv.z, a);
                a = fma((double)xv.w, (double)wv.w, a);
            }
            #pragma unroll
            for (int off = 32; off > 0; off >>= 1) a += __shfl_xor(a, off, 64);
            if (lane == c) dv = a;
        }
        double cv = dv; int ci = myi;
        double mx = 0.0, ssum = 0.0, keepv = 0.0; int keepi = 0;
        #pragma unroll 1
        for (int r = 0; r < kTopK; ++r) {
            double bv = cv; int bi = ci;
            #pragma unroll
            for (int off = 32; off > 0; off >>= 1) {
                const double ov = __shfl_xor(bv, off, 64);
                const int    oi = __shfl_xor(bi, off, 64);
                if (ov > bv || (ov == bv && oi < bi)) { bv = ov; bi = oi; }
            }
            if (r == 0) mx = bv;
            ssum += exp(bv - mx);
            if (lane == r) { keepv = bv; keepi = bi; }
            if (ci == bi) cv = -1.0e300;
        }
        if (lane < kTopK) {
            out[(size_t)row * kTopK + lane]           = (float)(exp(keepv - mx) / ssum);
            out[kIdxOff + (size_t)row * kTopK + lane] = (float)keepi;
        }
    }
}

extern "C" void kernel_launch(void* const* d_in, const int* in_sizes, int n_in,
                              void* d_out, int out_size, void* d_ws, size_t ws_size,
                              hipStream_t stream) {
    const float* x  = (const float*)d_in[0];
    const float* Wr = (const float*)d_in[1];
    float* out = (float*)d_out;
    float* Wt  = (float*)d_ws;
    _Float16* Wth = (_Float16*)((float*)d_ws + kWtF);
    _Float16* Wtl = (_Float16*)((float*)d_ws + kWtlF);
    float* pws = (float*)d_ws + kPartF;
    (void)in_sizes; (void)n_in; (void)out_size;

    const size_t need4 = (kPartF + 3 * kPartStride) * sizeof(float);  // 40MB
    const int nkc = (ws_size >= need4) ? 4 : 2;
    const int kchunk = kH / nkc;

    hipLaunchKernelGGL(prep_w, dim3(kH / 32, kE / 32), dim3(32, 32), 0, stream,
                       Wr, Wt, Wth, Wtl);
    hipLaunchKernelGGL(router_gemm_mfma, dim3(kTok / kBM, kE / kBN, nkc), dim3(256),
                       0, stream, x, Wth, Wtl, out + kLogitsOff, pws, kchunk);
    hipLaunchKernelGGL(combine_select, dim3(kTok / 4), dim3(256), 0, stream,
                       x, Wt, pws, out, nkc - 1);
}

// Round 5
// 215.439 us; speedup vs baseline: 7.4988x; 1.5045x over previous
//
#include <hip/hip_runtime.h>
#include <math.h>
#include <float.h>

typedef _Float16 half8 __attribute__((ext_vector_type(8)));
typedef float f32x4 __attribute__((ext_vector_type(4)));

namespace {
constexpr int kH = 8192, kE = 256, kTopK = 8, kTok = 8192;
constexpr int kIdxOff = kTok * kTopK;          // 65536
constexpr int kLogitsOff = 2 * kTok * kTopK;   // 131072
constexpr int kBM = 128, kBN = 128, kBK = 32;
constexpr int kPadH = 40;                      // LDS row stride in halfs (80B)
constexpr int kCand = 16;
constexpr float kEps = 5e-5f;                  // gap-trust margin (~12x max fp16x3 err)
constexpr float kInvScale = 1.0f / 262144.0f;  // 2^-18 (x*2^10, W*2^8)
// ws layout in floats: Wt fp32 [256][8192] | Wth fp16 | Wtl fp16 | partials
constexpr size_t kWtF   = (size_t)kE * kH;             // 8MB
constexpr size_t kWtlF  = kWtF + (size_t)kE * kH / 2;  // Wth is 4MB
constexpr size_t kPartF = kWtF + (size_t)kE * kH;      // 16MB offset
constexpr size_t kPartStride = (size_t)kTok * kE;      // 8MB per partial
}

// ---------- Kernel A: W[k][e] -> Wt fp32 [e][k], Wth/Wtl fp16 (W*256 split) --
__global__ __launch_bounds__(1024)
void prep_w(const float* __restrict__ W, float* __restrict__ Wt,
            _Float16* __restrict__ Wth, _Float16* __restrict__ Wtl) {
    __shared__ float tile[32][33];
    const int k0 = blockIdx.x * 32, e0 = blockIdx.y * 32;
    const int tx = threadIdx.x, ty = threadIdx.y;
    tile[ty][tx] = W[(size_t)(k0 + ty) * kE + (e0 + tx)];
    __syncthreads();
    const float v = tile[tx][ty];
    const size_t o = (size_t)(e0 + ty) * kH + (k0 + tx);
    Wt[o] = v;
    const float vs = v * 256.0f;
    const _Float16 h = (_Float16)vs;
    Wth[o] = h;
    Wtl[o] = (_Float16)(vs - (float)h);
}

// ---------- Kernel B: fp16x3 MFMA GEMM, 128x128 tile, split-K -----------------
__global__ __launch_bounds__(256, 2)
void router_gemm_mfma(const float* __restrict__ x,
                      const _Float16* __restrict__ Wth,
                      const _Float16* __restrict__ Wtl,
                      float* __restrict__ p0, float* __restrict__ pws,
                      int kchunk)
{
    __shared__ _Float16 sxh[kBM][kPadH], sxl[kBM][kPadH];
    __shared__ _Float16 swh[kBN][kPadH], swl[kBN][kPadH];

    const int tid  = threadIdx.x;
    const int lane = tid & 63;
    const int w    = tid >> 6;
    const int wm   = w >> 1, wn = w & 1;
    const int t0   = blockIdx.x * kBM;
    const int e0   = blockIdx.y * kBN;
    const int kc   = blockIdx.z;
    const int kbase = kc * kchunk;
    const int nsteps = kchunk / kBK;

    f32x4 acc[4][4];
    #pragma unroll
    for (int m = 0; m < 4; ++m)
        #pragma unroll
        for (int n = 0; n < 4; ++n) {
            acc[m][n][0] = 0.f; acc[m][n][1] = 0.f;
            acc[m][n][2] = 0.f; acc[m][n][3] = 0.f;
        }

    const int srow = tid >> 1;
    const int scg  = (tid & 1) << 4;
    const float*    xp  = x   + (size_t)(t0 + srow) * kH + kbase + scg;
    const _Float16* whp = Wth + (size_t)(e0 + srow) * kH + kbase + scg;
    const _Float16* wlp = Wtl + (size_t)(e0 + srow) * kH + kbase + scg;

    float4 xv0, xv1, xv2, xv3;
    uint4  wh0, wh1, wl0, wl1;
    {
        xv0 = *reinterpret_cast<const float4*>(xp);
        xv1 = *reinterpret_cast<const float4*>(xp + 4);
        xv2 = *reinterpret_cast<const float4*>(xp + 8);
        xv3 = *reinterpret_cast<const float4*>(xp + 12);
        wh0 = *reinterpret_cast<const uint4*>(whp);
        wh1 = *reinterpret_cast<const uint4*>(whp + 8);
        wl0 = *reinterpret_cast<const uint4*>(wlp);
        wl1 = *reinterpret_cast<const uint4*>(wlp + 8);
    }

    const int fr = lane & 15;
    const int fk = (lane >> 4) << 3;

    for (int t = 0; t < nsteps; ++t) {
        float xf[16];
        xf[0]=xv0.x; xf[1]=xv0.y; xf[2]=xv0.z; xf[3]=xv0.w;
        xf[4]=xv1.x; xf[5]=xv1.y; xf[6]=xv1.z; xf[7]=xv1.w;
        xf[8]=xv2.x; xf[9]=xv2.y; xf[10]=xv2.z; xf[11]=xv2.w;
        xf[12]=xv3.x; xf[13]=xv3.y; xf[14]=xv3.z; xf[15]=xv3.w;
        half8 h0, h1, l0, l1;
        #pragma unroll
        for (int i = 0; i < 8; ++i) {
            const float sA = xf[i] * 1024.0f;
            const _Float16 hA = (_Float16)sA;
            h0[i] = hA; l0[i] = (_Float16)(sA - (float)hA);
            const float sB = xf[i + 8] * 1024.0f;
            const _Float16 hB = (_Float16)sB;
            h1[i] = hB; l1[i] = (_Float16)(sB - (float)hB);
        }
        *reinterpret_cast<half8*>(&sxh[srow][scg])     = h0;
        *reinterpret_cast<half8*>(&sxh[srow][scg + 8]) = h1;
        *reinterpret_cast<half8*>(&sxl[srow][scg])     = l0;
        *reinterpret_cast<half8*>(&sxl[srow][scg + 8]) = l1;
        *reinterpret_cast<uint4*>(&swh[srow][scg])     = wh0;
        *reinterpret_cast<uint4*>(&swh[srow][scg + 8]) = wh1;
        *reinterpret_cast<uint4*>(&swl[srow][scg])     = wl0;
        *reinterpret_cast<uint4*>(&swl[srow][scg + 8]) = wl1;
        __syncthreads();

        if (t + 1 < nsteps) {
            const size_t o = (size_t)(t + 1) * kBK;
            xv0 = *reinterpret_cast<const float4*>(xp + o);
            xv1 = *reinterpret_cast<const float4*>(xp + o + 4);
            xv2 = *reinterpret_cast<const float4*>(xp + o + 8);
            xv3 = *reinterpret_cast<const float4*>(xp + o + 12);
            wh0 = *reinterpret_cast<const uint4*>(whp + o);
            wh1 = *reinterpret_cast<const uint4*>(whp + o + 8);
            wl0 = *reinterpret_cast<const uint4*>(wlp + o);
            wl1 = *reinterpret_cast<const uint4*>(wlp + o + 8);
        }

        half8 ah[4], al[4];
        #pragma unroll
        for (int m = 0; m < 4; ++m) {
            ah[m] = *reinterpret_cast<const half8*>(&sxh[(wm << 6) + (m << 4) + fr][fk]);
            al[m] = *reinterpret_cast<const half8*>(&sxl[(wm << 6) + (m << 4) + fr][fk]);
        }
        #pragma unroll
        for (int n = 0; n < 4; ++n) {
            const half8 bh = *reinterpret_cast<const half8*>(&swh[(wn << 6) + (n << 4) + fr][fk]);
            const half8 bl = *reinterpret_cast<const half8*>(&swl[(wn << 6) + (n << 4) + fr][fk]);
            #pragma unroll
            for (int m = 0; m < 4; ++m) {
                acc[m][n] = __builtin_amdgcn_mfma_f32_16x16x32_f16(ah[m], bh, acc[m][n], 0, 0, 0);
                acc[m][n] = __builtin_amdgcn_mfma_f32_16x16x32_f16(ah[m], bl, acc[m][n], 0, 0, 0);
                acc[m][n] = __builtin_amdgcn_mfma_f32_16x16x32_f16(al[m], bh, acc[m][n], 0, 0, 0);
            }
        }
        __syncthreads();
    }

    float* dst = (kc == 0) ? p0 : (pws + (size_t)(kc - 1) * kPartStride);
    const int r0 = (lane >> 4) << 2;
    const int c0 = lane & 15;
    #pragma unroll
    for (int m = 0; m < 4; ++m)
        #pragma unroll
        for (int n = 0; n < 4; ++n) {
            const int col = e0 + (wn << 6) + (n << 4) + c0;
            #pragma unroll
            for (int r = 0; r < 4; ++r) {
                const int row = t0 + (wm << 6) + (m << 4) + r0 + r;
                dst[(size_t)row * kE + col] = acc[m][n][r] * kInvScale;
            }
        }
}

// ---------- Kernel C: combine + select + (rare) ILP-4 fp64 refine ------------
#define ARGMAX_ROUND(r)                                                        \
    {                                                                          \
        float bv = v0; int bi = (lane << 2);                                   \
        if (v1 > bv) { bv = v1; bi = (lane << 2) + 1; }                        \
        if (v2 > bv) { bv = v2; bi = (lane << 2) + 2; }                        \
        if (v3 > bv) { bv = v3; bi = (lane << 2) + 3; }                        \
        _Pragma("unroll")                                                      \
        for (int off = 32; off > 0; off >>= 1) {                               \
            const float ov = __shfl_xor(bv, off, 64);                          \
            const int   oi = __shfl_xor(bi, off, 64);                          \
            if (ov > bv || (ov == bv && oi < bi)) { bv = ov; bi = oi; }        \
        }                                                                      \
        if (lane == (r)) { myv = bv; myi = bi; }                               \
        if ((bi >> 2) == lane) {                                               \
            const int m = bi & 3;                                              \
            if      (m == 0) v0 = -FLT_MAX;                                    \
            else if (m == 1) v1 = -FLT_MAX;                                    \
            else if (m == 2) v2 = -FLT_MAX;                                    \
            else             v3 = -FLT_MAX;                                    \
        }                                                                      \
    }

__global__ __launch_bounds__(256)
void combine_select(const float* __restrict__ x, const float* __restrict__ Wt,
                    const float* __restrict__ pws, float* __restrict__ out,
                    int npart)
{
    const int lane = threadIdx.x & 63;
    const int w    = threadIdx.x >> 6;
    const int row  = blockIdx.x * 4 + w;
    float* logits = out + kLogitsOff;
    const size_t rb = (size_t)row * kE + (lane << 2);

    float4 s = *reinterpret_cast<const float4*>(logits + rb);
    for (int p = 0; p < npart; ++p) {
        const float4 q = *reinterpret_cast<const float4*>(pws + (size_t)p * kPartStride + rb);
        s.x += q.x; s.y += q.y; s.z += q.z; s.w += q.w;
    }
    *reinterpret_cast<float4*>(logits + rb) = s;

    float v0 = s.x, v1 = s.y, v2 = s.z, v3 = s.w;
    float myv = -FLT_MAX; int myi = -1;

    // ranks 0..8 — all the gap test needs
    #pragma unroll
    for (int r = 0; r < 9; ++r) ARGMAX_ROUND(r)

    const float nv = __shfl_down(myv, 1, 64);
    const unsigned long long amb = __ballot(lane < 8 && (myv - nv) < kEps);

    if (amb == 0ull) {
        const float m = __shfl(myv, 0, 64);
        const float e = (lane < kTopK) ? expf(myv - m) : 0.f;
        float t = e;
        #pragma unroll
        for (int off = 1; off < 8; off <<= 1) t += __shfl_xor(t, off, 64);
        if (lane < kTopK) {
            out[(size_t)row * kTopK + lane]           = e / t;
            out[kIdxOff + (size_t)row * kTopK + lane] = (float)myi;
        }
    } else {
        // finish the candidate set (ranks 9..15) — wave-uniform branch
        #pragma unroll
        for (int r = 9; r < kCand; ++r) ARGMAX_ROUND(r)

        // fp64 recompute of 16 candidates, 4-way ILP
        const float* xr = x + (size_t)row * kH;
        double dv = -1.0e300;
        #pragma unroll 1
        for (int cg = 0; cg < kCand; cg += 4) {
            const int i0 = __shfl(myi, cg + 0, 64);
            const int i1 = __shfl(myi, cg + 1, 64);
            const int i2 = __shfl(myi, cg + 2, 64);
            const int i3 = __shfl(myi, cg + 3, 64);
            const float* w0 = Wt + (size_t)i0 * kH;
            const float* w1 = Wt + (size_t)i1 * kH;
            const float* w2 = Wt + (size_t)i2 * kH;
            const float* w3 = Wt + (size_t)i3 * kH;
            double a0 = 0.0, a1 = 0.0, a2 = 0.0, a3 = 0.0;
            for (int k = (lane << 2); k < kH; k += 256) {
                const float4 xv = *reinterpret_cast<const float4*>(xr + k);
                const float4 q0 = *reinterpret_cast<const float4*>(w0 + k);
                const float4 q1 = *reinterpret_cast<const float4*>(w1 + k);
                const float4 q2 = *reinterpret_cast<const float4*>(w2 + k);
                const float4 q3 = *reinterpret_cast<const float4*>(w3 + k);
                a0 = fma((double)xv.x, (double)q0.x, a0);
                a1 = fma((double)xv.x, (double)q1.x, a1);
                a2 = fma((double)xv.x, (double)q2.x, a2);
                a3 = fma((double)xv.x, (double)q3.x, a3);
                a0 = fma((double)xv.y, (double)q0.y, a0);
                a1 = fma((double)xv.y, (double)q1.y, a1);
                a2 = fma((double)xv.y, (double)q2.y, a2);
                a3 = fma((double)xv.y, (double)q3.y, a3);
                a0 = fma((double)xv.z, (double)q0.z, a0);
                a1 = fma((double)xv.z, (double)q1.z, a1);
                a2 = fma((double)xv.z, (double)q2.z, a2);
                a3 = fma((double)xv.z, (double)q3.z, a3);
                a0 = fma((double)xv.w, (double)q0.w, a0);
                a1 = fma((double)xv.w, (double)q1.w, a1);
                a2 = fma((double)xv.w, (double)q2.w, a2);
                a3 = fma((double)xv.w, (double)q3.w, a3);
            }
            #pragma unroll
            for (int off = 32; off > 0; off >>= 1) {
                a0 += __shfl_xor(a0, off, 64);
                a1 += __shfl_xor(a1, off, 64);
                a2 += __shfl_xor(a2, off, 64);
                a3 += __shfl_xor(a3, off, 64);
            }
            if (lane == cg + 0) dv = a0;
            if (lane == cg + 1) dv = a1;
            if (lane == cg + 2) dv = a2;
            if (lane == cg + 3) dv = a3;
        }

        double cv = dv; int ci = myi;
        double mx = 0.0, ssum = 0.0, keepv = 0.0; int keepi = 0;
        #pragma unroll 1
        for (int r = 0; r < kTopK; ++r) {
            double bv = cv; int bi = ci;
            #pragma unroll
            for (int off = 32; off > 0; off >>= 1) {
                const double ov = __shfl_xor(bv, off, 64);
                const int    oi = __shfl_xor(bi, off, 64);
                if (ov > bv || (ov == bv && oi < bi)) { bv = ov; bi = oi; }
            }
            if (r == 0) mx = bv;
            ssum += exp(bv - mx);
            if (lane == r) { keepv = bv; keepi = bi; }
            if (ci == bi) cv = -1.0e300;
        }
        if (lane < kTopK) {
            out[(size_t)row * kTopK + lane]           = (float)(exp(keepv - mx) / ssum);
            out[kIdxOff + (size_t)row * kTopK + lane] = (float)keepi;
        }
    }
}

extern "C" void kernel_launch(void* const* d_in, const int* in_sizes, int n_in,
                              void* d_out, int out_size, void* d_ws, size_t ws_size,
                              hipStream_t stream) {
    const float* x  = (const float*)d_in[0];
    const float* Wr = (const float*)d_in[1];
    float* out = (float*)d_out;
    float* Wt  = (float*)d_ws;
    _Float16* Wth = (_Float16*)((float*)d_ws + kWtF);
    _Float16* Wtl = (_Float16*)((float*)d_ws + kWtlF);
    float* pws = (float*)d_ws + kPartF;
    (void)in_sizes; (void)n_in; (void)out_size;

    const size_t need4 = (kPartF + 3 * kPartStride) * sizeof(float);  // 40MB
    const int nkc = (ws_size >= need4) ? 4 : 2;
    const int kchunk = kH / nkc;

    hipLaunchKernelGGL(prep_w, dim3(kH / 32, kE / 32), dim3(32, 32), 0, stream,
                       Wr, Wt, Wth, Wtl);
    hipLaunchKernelGGL(router_gemm_mfma, dim3(kTok / kBM, kE / kBN, nkc), dim3(256),
                       0, stream, x, Wth, Wtl, out + kLogitsOff, pws, kchunk);
    hipLaunchKernelGGL(combine_select, dim3(kTok / 4), dim3(256), 0, stream,
                       x, Wt, pws, out, nkc - 1);
}